// Round 1
// baseline (35.242 us; speedup 1.0000x reference)
//
#include <hip/hip_runtime.h>

// Filter-bank row offsets per order (order i block starts after sum_{j<i} C(60,j)):
//   OFF1 = 0, OFF2 = C(60,1) = 60, OFF3 = 60+1770 = 1830,
//   OFF4 = 1830+34220 = 36050, OFF5 = 36050+487635 = 523685; total 5985197 = perms.
#define OFF2 60
#define OFF3 1830
#define OFF4 36050
#define OFF5 523685

__global__ __launch_bounds__(128) void brutesolver_kernel(
        const int* __restrict__ x,      // [16] int32 in {0,1}
        const float* __restrict__ w,    // [perms] correlation weights
        const float* __restrict__ den_b,// [1] bias
        float* __restrict__ out) {      // [3*16] fp32
    // P_k[c] = sum_{v=0}^{c-1} C(59-v, k)  (prefix tables for lex combination rank)
    __shared__ int P1[61], P2[61], P3[61], P4[61];
    __shared__ int s_occ[16];
    __shared__ int s_m;
    __shared__ float sred[128];

    const int tid = threadIdx.x;
    const int pix = blockIdx.x;          // 16 pixels
    const int py = pix >> 2, px = pix & 3;

    if (tid == 0) {
        long long p1 = 0, p2 = 0, p3 = 0, p4 = 0;
        for (int c = 0; c <= 60; ++c) {
            P1[c] = (int)p1; P2[c] = (int)p2; P3[c] = (int)p3; P4[c] = (int)p4;
            if (c < 60) {
                long long n = 59 - c;
                p1 += n;
                p2 += n * (n - 1) / 2;
                p3 += n * (n - 1) * (n - 2) / 6;
                p4 += n * (n - 1) * (n - 2) * (n - 3) / 24;
            }
        }
        // Occupied taps for this pixel. Tap k -> (dy,dx)=(k/11,k%11),
        // reads original cell (py+dy-5, px+dx-5). k<60 => causal half-plane.
        int m = 0;
        for (int k = 0; k < 60; ++k) {
            int iy = py + k / 11 - 5;
            int ix = px + k % 11 - 5;
            if (iy >= 0 && iy < 4 && ix >= 0 && ix < 4 && x[iy * 4 + ix] == 1)
                s_occ[m++] = k;   // m <= 4*py+px <= 15
        }
        s_m = m;
    }
    __syncthreads();

    const int m = s_m;
    float acc = 0.f;

    // order 1: rank(c0) = c0
    for (int a = tid; a < m; a += 128) acc += w[s_occ[a]];

    // orders 2..5: distribute by the first PAIR of the subset
    const int npairs = m * (m - 1) / 2;
    for (int p = tid; p < npairs; p += 128) {
        int a = 0, r = p;
        while (r >= m - 1 - a) { r -= m - 1 - a; ++a; }
        const int bidx = a + 1 + r;
        const int c0 = s_occ[a], c1 = s_occ[bidx];

        // order 2: rank = P1[c0] + (c1 - c0 - 1)
        acc += w[OFF2 + P1[c0] + (c1 - c0 - 1)];

        // partial ranks of prefix (c0,c1) for final orders 3/4/5
        const int b3 = P2[c0] + P1[c1] - P1[c0 + 1];
        const int b4 = P3[c0] + P2[c1] - P2[c0 + 1];
        const int b5 = P4[c0] + P3[c1] - P3[c0 + 1];

        for (int ci = bidx + 1; ci < m; ++ci) {
            const int c2 = s_occ[ci];
            acc += w[OFF3 + b3 + (c2 - c1 - 1)];
            const int b4c = b4 + P1[c2] - P1[c1 + 1];
            const int b5c = b5 + P2[c2] - P2[c1 + 1];
            for (int di = ci + 1; di < m; ++di) {
                const int c3 = s_occ[di];
                acc += w[OFF4 + b4c + (c3 - c2 - 1)];
                const int b5d = b5c + P1[c3] - P1[c2 + 1];
                for (int ei = di + 1; ei < m; ++ei) {
                    const int c4 = s_occ[ei];
                    acc += w[OFF5 + b5d + (c4 - c3 - 1)];
                }
            }
        }
    }

    // block reduction
    sred[tid] = acc;
    __syncthreads();
    for (int s = 64; s > 0; s >>= 1) {
        if (tid < s) sred[tid] += sred[tid + s];
        __syncthreads();
    }

    if (tid == 0) {
        const float y = sred[0] + den_b[0];
        out[pix]      = -100.0f;  // channel 0
        out[16 + pix] = -y;       // channel 1
        out[32 + pix] = y;        // channel 2
    }
}

extern "C" void kernel_launch(void* const* d_in, const int* in_sizes, int n_in,
                              void* d_out, int out_size, void* d_ws, size_t ws_size,
                              hipStream_t stream) {
    // inputs: 0=x(int32[16]) 1=filters(unused) 2=order_index(unused)
    //         3=w_corr(fp32[perms]) 4=den_w(unused) 5=den_b(fp32[1])
    const int*   x     = (const int*)d_in[0];
    const float* w     = (const float*)d_in[3];
    const float* den_b = (const float*)d_in[5];
    float* out = (float*)d_out;
    brutesolver_kernel<<<16, 128, 0, stream>>>(x, w, den_b, out);
}

// Round 2
// 12.949 us; speedup vs baseline: 2.7215x; 2.7215x over previous
//
#include <hip/hip_runtime.h>

// Filter-bank row offsets per order: OFF_i = sum_{j<i} C(60,j), OFF1 = 0.
#define OFF2 60
#define OFF3 1830
#define OFF4 36050
#define OFF5 523685
// Totals check: OFF5 + C(60,5) = 523685 + 5461512 = 5985197 = perms.

__global__ __launch_bounds__(256) void brutesolver_kernel(
        const int* __restrict__ x,      // [16] int32 in {0,1}
        const float* __restrict__ w,    // [perms] correlation weights
        const float* __restrict__ den_b,// [1] bias
        float* __restrict__ out) {      // [3*16] fp32
    // P[k][c] = sum_{v<c} C(59-v,k) = C(60,k+1) - C(60-c,k+1); P[0][c] = c.
    __shared__ int   P[5][61];
    __shared__ int   CB[16][6];         // C(n,k), n<=15 (index-combination decode)
    __shared__ int   s_occ[16];
    __shared__ int   s_m;
    __shared__ int   scnt[256];
    __shared__ int   sbuf[4944];        // max total subsets: sum C(15,i),i=1..5 = 4943
    __shared__ float sred[256];

    const int tid = threadIdx.x;
    const int pix = blockIdx.x;         // 16 pixels
    const int py = pix >> 2, px = pix & 3;

    // ---- occupancy list via wave-0 ballot (sorted by tap code) ----
    if (tid < 64) {
        bool flag = false;
        if (tid < 60) {
            int iy = py + tid / 11 - 5;  // tap k=tid -> (dy,dx)=(k/11,k%11)
            int ix = px + tid % 11 - 5;
            flag = (iy >= 0) && (iy < 4) && (ix >= 0) && (ix < 4) && (x[iy * 4 + ix] == 1);
        }
        unsigned long long mask = __ballot(flag);
        if (flag) s_occ[__popcll(mask & ((1ull << tid) - 1))] = tid;
        if (tid == 0) s_m = (int)__popcll(mask);
    }
    // ---- rank prefix tables, parallel closed form ----
    if (tid <= 60) {
        long long n = 60 - tid;
        P[0][tid] = tid;
        P[1][tid] = 1770    - (int)(n * (n - 1) / 2);
        P[2][tid] = 34220   - (int)(n * (n - 1) * (n - 2) / 6);
        P[3][tid] = 487635  - (int)(n * (n - 1) * (n - 2) * (n - 3) / 24);
        P[4][tid] = 5461512 - (int)(n * (n - 1) * (n - 2) * (n - 3) * (n - 4) / 120);
    }
    if (tid < 16) {
        long long n = tid;
        CB[tid][0] = 1;
        CB[tid][1] = tid;
        CB[tid][2] = (int)(n * (n - 1) / 2);
        CB[tid][3] = (int)(n * (n - 1) * (n - 2) / 6);
        CB[tid][4] = (int)(n * (n - 1) * (n - 2) * (n - 3) / 24);
        CB[tid][5] = (int)(n * (n - 1) * (n - 2) * (n - 3) * (n - 4) / 120);
    }
    __syncthreads();

    const int m = s_m;
    const int nPairs = CB[m][2];
    const int nTrip  = CB[m][3];

    // ---- decode my assigned items (<=1 single, <=1 pair, <=2 triples) ----
    int pA = -1, pB = -1;
    if (tid < nPairs) {
        int q = tid, a = 0;
        while (CB[m - 1 - a][1] <= q) { q -= CB[m - 1 - a][1]; ++a; }
        pA = a; pB = a + 1 + q;
    }
    int tA0 = -1, tB0 = 0, tC0 = 0, tA1 = -1, tB1 = 0, tC1 = 0;
    int cnt = (tid < m ? 1 : 0) + (pA >= 0 ? 1 : 0);
    if (tid < nTrip) {
        int q = tid, a = 0;
        while (CB[m - 1 - a][2] <= q) { q -= CB[m - 1 - a][2]; ++a; }
        int b = a + 1;
        while (CB[m - 1 - b][1] <= q) { q -= CB[m - 1 - b][1]; ++b; }
        tA0 = a; tB0 = b; tC0 = b + 1 + q;
        int t = m - 1 - tC0;
        cnt += 1 + t + t * (t - 1) / 2;
    }
    if (tid + 256 < nTrip) {
        int q = tid + 256, a = 0;
        while (CB[m - 1 - a][2] <= q) { q -= CB[m - 1 - a][2]; ++a; }
        int b = a + 1;
        while (CB[m - 1 - b][1] <= q) { q -= CB[m - 1 - b][1]; ++b; }
        tA1 = a; tB1 = b; tC1 = b + 1 + q;
        int t = m - 1 - tC1;
        cnt += 1 + t + t * (t - 1) / 2;
    }

    // ---- exclusive prefix over per-thread emission counts ----
    scnt[tid] = cnt;
    __syncthreads();
    for (int off = 1; off < 256; off <<= 1) {
        int v = (tid >= off) ? scnt[tid - off] : 0;
        __syncthreads();
        scnt[tid] += v;
        __syncthreads();
    }
    int pos = scnt[tid] - cnt;
    const int T = scnt[255];

    // ---- phase 1: emit ranks into LDS ----
    if (tid < m) sbuf[pos++] = s_occ[tid];                       // order 1: rank = c0
    if (pA >= 0) {
        int c0 = s_occ[pA], c1 = s_occ[pB];
        sbuf[pos++] = OFF2 + P[1][c0] + (c1 - c0 - 1);           // order 2
    }
    auto emitTriple = [&](int ia, int ib, int ic) {
        int c0 = s_occ[ia], c1 = s_occ[ib], c2 = s_occ[ic];
        sbuf[pos++] = OFF3 + P[2][c0] + P[1][c1] - P[1][c0 + 1] + (c2 - c1 - 1);
        int b4 = P[3][c0] + P[2][c1] - P[2][c0 + 1] + P[1][c2] - P[1][c1 + 1];
        int b5 = P[4][c0] + P[3][c1] - P[3][c0 + 1] + P[2][c2] - P[2][c1 + 1];
        for (int di = ic + 1; di < m; ++di) {
            int c3 = s_occ[di];
            sbuf[pos++] = OFF4 + b4 + (c3 - c2 - 1);
            int b5d = b5 + P[1][c3] - P[1][c2 + 1];
            for (int ei = di + 1; ei < m; ++ei) {
                int c4 = s_occ[ei];
                sbuf[pos++] = OFF5 + b5d + (c4 - c3 - 1);
            }
        }
    };
    if (tA0 >= 0) emitTriple(tA0, tB0, tC0);
    if (tA1 >= 0) emitTriple(tA1, tB1, tC1);
    __syncthreads();

    // ---- phase 2: balanced gather, 4 loads in flight ----
    float a0 = 0.f, a1 = 0.f, a2 = 0.f, a3 = 0.f;
    int g = tid;
    for (; g + 768 < T; g += 1024) {
        a0 += w[sbuf[g]];
        a1 += w[sbuf[g + 256]];
        a2 += w[sbuf[g + 512]];
        a3 += w[sbuf[g + 768]];
    }
    for (; g < T; g += 256) a0 += w[sbuf[g]];
    float acc = (a0 + a1) + (a2 + a3);

    // ---- block reduce + write ----
    sred[tid] = acc;
    __syncthreads();
    for (int s = 128; s > 0; s >>= 1) {
        if (tid < s) sred[tid] += sred[tid + s];
        __syncthreads();
    }
    if (tid == 0) {
        float y = sred[0] + den_b[0];
        out[pix]      = -100.0f;
        out[16 + pix] = -y;
        out[32 + pix] = y;
    }
}

extern "C" void kernel_launch(void* const* d_in, const int* in_sizes, int n_in,
                              void* d_out, int out_size, void* d_ws, size_t ws_size,
                              hipStream_t stream) {
    // inputs: 0=x(int32[16]) 1=filters(unused) 2=order_index(unused)
    //         3=w_corr(fp32[perms]) 4=den_w(unused) 5=den_b(fp32[1])
    const int*   x     = (const int*)d_in[0];
    const float* w     = (const float*)d_in[3];
    const float* den_b = (const float*)d_in[5];
    float* out = (float*)d_out;
    brutesolver_kernel<<<16, 256, 0, stream>>>(x, w, den_b, out);
}